// Round 15
// baseline (143.056 us; speedup 1.0000x reference)
//
#include <hip/hip_runtime.h>

#define N_NODES 100000
#define N_EDGES 1600000
#define D_FEAT 32

#define NWIN 512
#define RPW  ((N_NODES + NWIN - 1) / NWIN)   // 196 rows per window (fits in 8 bits)
#define WPAD 16                               // pad window cursors to 64B lines
#define CAP  4096                             // per-window capacity (mean 3125, +17 sigma)

// pack: col (17 bits) << 15 | val_fix (15 bits), val_fix = round(val * 2^19)
#define VAL_SCALE 524288.0f
#define VAL_INV   (1.0f / 524288.0f)

// edge-block geometry for bucket
#define EB_BS  256
#define EB_EPT 16
#define EB_EPB (EB_BS * EB_EPT)               // 4096 edges per block
#define EB_NB  ((N_EDGES + EB_EPB - 1) / EB_EPB)  // 391 blocks

__device__ __forceinline__ unsigned short f2bf(float f) {
    unsigned u = __float_as_uint(f);
    unsigned r = u + 0x7fffu + ((u >> 16) & 1u);   // round-to-nearest-even
    return (unsigned short)(r >> 16);
}
__device__ __forceinline__ float bfl(unsigned u) { return __uint_as_float(u << 16); }
__device__ __forceinline__ float bfh(unsigned u) { return __uint_as_float(u & 0xffff0000u); }

// ---------------- tiny cursor init ----------------

__global__ __launch_bounds__(256) void cursor_kernel(int* __restrict__ win_cursor) {
    int i = blockIdx.x * 256 + threadIdx.x;
    if (i < NWIN) win_cursor[i * WPAD] = i * CAP;
}

// ---------------- counting sort into per-window piles (once per call) ----------------

// LDS-staged bucket: block-sort 4096 edges by window in LDS, then copy out
// linearly so global stores coalesce into full-line runs per window.
// Tail: grid-stride feat->bf16 conversion (consumed two kernels later).
__global__ __launch_bounds__(EB_BS) void bucket_kernel(const int* __restrict__ row,
                                                       const int* __restrict__ col,
                                                       const float* __restrict__ vals,
                                                       int* __restrict__ win_cursor,
                                                       uint2* __restrict__ pile,
                                                       const float* __restrict__ feat,
                                                       unsigned short* __restrict__ feat16,
                                                       int n4) {
    __shared__ int wcnt[NWIN];     // histogram, then reused as placement cursor
    __shared__ int lbase[NWIN];    // block-local exclusive scan
    __shared__ int wbase[NWIN];    // global reserved base per window
    __shared__ int ps[EB_BS];      // pair-sum scan workspace
    __shared__ uint2 stage[EB_EPB];// 32 KB staging
    int t = threadIdx.x;
    for (int i = t; i < NWIN; i += EB_BS) wcnt[i] = 0;
    __syncthreads();

    int base = blockIdx.x * EB_EPB;
    unsigned pk_[EB_EPT];   // packed {col|val}
    int wr_[EB_EPT];        // (w<<8) | local_row, or -1
#pragma unroll
    for (int i = 0; i < EB_EPT; ++i) {
        int e = base + i * EB_BS + t;
        if (e < N_EDGES) {
            int r = row[e];
            int w = r / RPW;
            unsigned fx = (unsigned)__float2int_rn(vals[e] * VAL_SCALE);
            if (fx > 0x7FFFu) fx = 0x7FFFu;
            pk_[i] = ((unsigned)col[e] << 15) | fx;
            wr_[i] = (w << 8) | (r - w * RPW);
            atomicAdd(&wcnt[w], 1);
        } else wr_[i] = -1;
    }
    __syncthreads();

    // exclusive scan of wcnt[0..511] -> lbase (2 elements per thread)
    int c0 = wcnt[2 * t], c1 = wcnt[2 * t + 1];
    ps[t] = c0 + c1;
    __syncthreads();
    for (int off = 1; off < EB_BS; off <<= 1) {
        int u = (t >= off) ? ps[t - off] : 0;
        __syncthreads();
        ps[t] += u;
        __syncthreads();
    }
    int pex = ps[t] - (c0 + c1);
    lbase[2 * t]     = pex;
    lbase[2 * t + 1] = pex + c0;
    __syncthreads();

    // reserve global space per window; reset cursor to local base
    for (int i = t; i < NWIN; i += EB_BS) {
        int cw = wcnt[i];
        wbase[i] = cw ? atomicAdd(&win_cursor[i * WPAD], cw) : 0;
    }
    __syncthreads();
    for (int i = t; i < NWIN; i += EB_BS) wcnt[i] = lbase[i];
    __syncthreads();

    // place edges into LDS staging, sorted by window
#pragma unroll
    for (int i = 0; i < EB_EPT; ++i) {
        if (wr_[i] < 0) continue;
        int w = wr_[i] >> 8;
        int loc = atomicAdd(&wcnt[w], 1);
        stage[loc] = make_uint2(pk_[i], (unsigned)wr_[i]);
    }
    __syncthreads();

    // linear LDS -> global copy: consecutive i in one window hit consecutive
    // pile slots -> coalesced full-line stores (except at window boundaries)
    int nedge = N_EDGES - base; if (nedge > EB_EPB) nedge = EB_EPB;
    for (int i = t; i < nedge; i += EB_BS) {
        uint2 ed = stage[i];
        int w = ed.y >> 8;
        int pos = wbase[w] + (i - lbase[w]);
        pile[pos] = make_uint2(ed.x, ed.y & 0xFFu);
    }

    // tail: feat -> bf16 mirror (grid-stride)
    for (int i = blockIdx.x * EB_BS + t; i < n4; i += EB_NB * EB_BS) {
        float4 f = reinterpret_cast<const float4*>(feat)[i];
        ushort4 o;
        o.x = f2bf(f.x); o.y = f2bf(f.y); o.z = f2bf(f.z); o.w = f2bf(f.w);
        reinterpret_cast<ushort4*>(feat16)[i] = o;
    }
}

// ---------------- gather macros ----------------

#define GATH(qq, pp) \
    uint4 qq = *(reinterpret_cast<const uint4*>(gsrc + (size_t)((pp) >> 15) * D_FEAT) + c)
#define ACC(qq, vv) \
    a0 += (vv) * bfl(qq.x); a1 += (vv) * bfh(qq.x); a2 += (vv) * bfl(qq.y); a3 += (vv) * bfh(qq.y); \
    a4 += (vv) * bfl(qq.z); a5 += (vv) * bfh(qq.z); a6 += (vv) * bfl(qq.w); a7 += (vv) * bfh(qq.w)

// ---------------- merged finesort + degree-perm + spmm pass 1 ----------------
// Phase 1: histogram pile rows -> scan -> CSR ranges
// Phase 2: window-local degree-sort -> lperm (LDS) + prr[slot]={beg,end,row} (global)
// Phase 3: scatter pile into CSR order: LDS cvl + global cv
// Phase 4: pull-spmm pass 1 from the LDS edge list in perm order.
__global__ __launch_bounds__(1024) void finesort_spmm1_kernel(const uint2* __restrict__ pile,
                               const int* __restrict__ win_cursor,
                               unsigned int* __restrict__ cvout,
                               int4* __restrict__ prr,
                               const unsigned short* __restrict__ gsrc,
                               unsigned short* __restrict__ g_out) {
    __shared__ int cnt[256];
    __shared__ int incl[256];
    __shared__ int cur[256];
    __shared__ int lbeg[256];
    __shared__ int dcur[32];
    __shared__ short lperm[256];
    __shared__ unsigned cvl[CAP];            // 16 KB
    int w = blockIdx.x, t = threadIdx.x;
    int rbeg = w * RPW;
    int rcnt = N_NODES - rbeg;
    if (rcnt > RPW) rcnt = RPW;
    if (rcnt < 0) rcnt = 0;
    int pbeg = w * CAP;
    int pend = win_cursor[w * WPAD];
    if (t < 256) cnt[t] = 0;
    if (t >= 256 && t < 288) *((int*)dcur + (t - 256)) = 0;   // dcur[0..31] reused as degree hist first
    __syncthreads();
    for (int i = pbeg + t; i < pend; i += 1024) atomicAdd(&cnt[pile[i].y], 1);
    __syncthreads();
    int v = 0;
    if (t < 256) { v = cnt[t]; incl[t] = v; }
    __syncthreads();
    for (int off = 1; off < 256; off <<= 1) {
        int u = (t < 256 && t >= off) ? incl[t - off] : 0;
        __syncthreads();
        if (t < 256) incl[t] += u;
        __syncthreads();
    }
    int ex = 0, dbin = 0;
    if (t < 256) {
        ex = incl[t] - v;
        cur[t] = ex;
        lbeg[t] = ex;
        if (t < rcnt) {
            dbin = v < 31 ? v : 31;
            atomicAdd(&dcur[dbin], 1);    // degree histogram
        }
    }
    __syncthreads();
    // exclusive scan of 32 degree bins (each lane sums its prefix; dcur becomes cursor)
    __shared__ int dex[32];
    if (t < 32) {
        int s = 0;
        for (int j = 0; j < t; ++j) s += dcur[j];
        dex[t] = s;
    }
    __syncthreads();
    if (t < 32) dcur[t] = dex[t];
    __syncthreads();
    if (t < rcnt) {
        int slot = atomicAdd(&dcur[dbin], 1);
        lperm[slot] = (short)t;
        prr[rbeg + slot] = make_int4(pbeg + ex, pbeg + ex + v, rbeg + t, 0);
    }
    __syncthreads();
    for (int i = pbeg + t; i < pend; i += 1024) {
        uint2 ed = pile[i];
        int pos = atomicAdd(&cur[ed.y], 1);
        cvl[pos] = ed.x;
        cvout[pbeg + pos] = ed.x;
    }
    __syncthreads();

    // ---- spmm pass 1 for this window's rows (perm order), edges from LDS ----
    int ntask = rcnt * 4;
    if (t < ntask) {
        int lr = lperm[t >> 2];
        int c = t & 3;
        int e = lbeg[lr];
        int end = incl[lr];
        float a0=0.f,a1=0.f,a2=0.f,a3=0.f,a4=0.f,a5=0.f,a6=0.f,a7=0.f;
        for (; e + 4 <= end; e += 4) {
            unsigned p0 = cvl[e + 0], p1 = cvl[e + 1], p2 = cvl[e + 2], p3 = cvl[e + 3];
            GATH(q0, p0); GATH(q1, p1); GATH(q2, p2); GATH(q3, p3);
            float v0 = (float)(p0 & 0x7FFFu) * VAL_INV;
            float v1 = (float)(p1 & 0x7FFFu) * VAL_INV;
            float v2 = (float)(p2 & 0x7FFFu) * VAL_INV;
            float v3 = (float)(p3 & 0x7FFFu) * VAL_INV;
            ACC(q0, v0); ACC(q1, v1); ACC(q2, v2); ACC(q3, v3);
        }
        for (; e < end; ++e) {
            unsigned p = cvl[e];
            float vv = (float)(p & 0x7FFFu) * VAL_INV;
            GATH(q, p);
            ACC(q, vv);
        }
        size_t base = (size_t)(rbeg + lr) * D_FEAT + c * 8;
        uint4 qi = *reinterpret_cast<const uint4*>(gsrc + base);
        float c0=bfl(qi.x), c1=bfh(qi.x), c2=bfl(qi.y), c3=bfh(qi.y);
        float c4=bfl(qi.z), c5=bfh(qi.z), c6=bfl(qi.w), c7=bfh(qi.w);
        uint4 o;
        o.x = (unsigned)f2bf(c0 - a0) | ((unsigned)f2bf(c1 - a1) << 16);
        o.y = (unsigned)f2bf(c2 - a2) | ((unsigned)f2bf(c3 - a3) << 16);
        o.z = (unsigned)f2bf(c4 - a4) | ((unsigned)f2bf(c5 - a5) << 16);
        o.w = (unsigned)f2bf(c6 - a6) | ((unsigned)f2bf(c7 - a7) << 16);
        *reinterpret_cast<uint4*>(g_out + base) = o;
    }
}

// ---------------- polynomial steps 2..4 (flat pull, perm order via prr) ----------------

// Uniform bf16-state step: cn = gsrc[r] - sum_e val * gsrc[col]  (f32 accumulate)
//   last==0: g_out[r] = bf16(cn)
//   last==1: h[r] = th0*f16[r] + th1*t1[r] + th2*t2[r] + th3*gsrc[r] + th4*cn
// 4 lanes per row (uint4 = 8 bf16 each); edge loop pipelined 8-deep for MLP.
__global__ __launch_bounds__(256) void spmm_kernel(const int4* __restrict__ prr,
                               const unsigned int* __restrict__ cv,
                               const unsigned short* __restrict__ gsrc,
                               unsigned short* __restrict__ g_out,
                               const unsigned short* __restrict__ f16,
                               const unsigned short* __restrict__ t1,
                               const unsigned short* __restrict__ t2,
                               const float* __restrict__ theta,
                               float* __restrict__ h,
                               int last) {
    int tid = blockIdx.x * blockDim.x + threadIdx.x;
    int i = tid >> 2;
    int c = tid & 3;
    if (i >= N_NODES) return;
    int4 rr = prr[i];
    int e = rr.x, end = rr.y, r = rr.z;
    float a0=0.f,a1=0.f,a2=0.f,a3=0.f,a4=0.f,a5=0.f,a6=0.f,a7=0.f;

    for (; e + 8 <= end; e += 8) {
        unsigned p0 = cv[e + 0], p1 = cv[e + 1], p2 = cv[e + 2], p3 = cv[e + 3];
        unsigned p4 = cv[e + 4], p5 = cv[e + 5], p6 = cv[e + 6], p7 = cv[e + 7];
        GATH(q0, p0); GATH(q1, p1); GATH(q2, p2); GATH(q3, p3);
        GATH(q4, p4); GATH(q5, p5); GATH(q6, p6); GATH(q7, p7);
        float v0 = (float)(p0 & 0x7FFFu) * VAL_INV;
        float v1 = (float)(p1 & 0x7FFFu) * VAL_INV;
        float v2 = (float)(p2 & 0x7FFFu) * VAL_INV;
        float v3 = (float)(p3 & 0x7FFFu) * VAL_INV;
        float v4 = (float)(p4 & 0x7FFFu) * VAL_INV;
        float v5 = (float)(p5 & 0x7FFFu) * VAL_INV;
        float v6 = (float)(p6 & 0x7FFFu) * VAL_INV;
        float v7 = (float)(p7 & 0x7FFFu) * VAL_INV;
        ACC(q0, v0); ACC(q1, v1); ACC(q2, v2); ACC(q3, v3);
        ACC(q4, v4); ACC(q5, v5); ACC(q6, v6); ACC(q7, v7);
    }
    for (; e + 4 <= end; e += 4) {
        unsigned p0 = cv[e + 0], p1 = cv[e + 1], p2 = cv[e + 2], p3 = cv[e + 3];
        GATH(q0, p0); GATH(q1, p1); GATH(q2, p2); GATH(q3, p3);
        float v0 = (float)(p0 & 0x7FFFu) * VAL_INV;
        float v1 = (float)(p1 & 0x7FFFu) * VAL_INV;
        float v2 = (float)(p2 & 0x7FFFu) * VAL_INV;
        float v3 = (float)(p3 & 0x7FFFu) * VAL_INV;
        ACC(q0, v0); ACC(q1, v1); ACC(q2, v2); ACC(q3, v3);
    }
    for (; e < end; ++e) {
        unsigned p = cv[e];
        float v = (float)(p & 0x7FFFu) * VAL_INV;
        GATH(q, p);
        ACC(q, v);
    }

    size_t base = (size_t)r * D_FEAT + c * 8;
    uint4 qi = *reinterpret_cast<const uint4*>(gsrc + base);   // identity (bf16, hot)
    float c0=bfl(qi.x), c1=bfh(qi.x), c2=bfl(qi.y), c3=bfh(qi.y);
    float c4=bfl(qi.z), c5=bfh(qi.z), c6=bfl(qi.w), c7=bfh(qi.w);
    float n0=c0-a0, n1=c1-a1, n2=c2-a2, n3=c3-a3, n4=c4-a4, n5=c5-a5, n6=c6-a6, n7=c7-a7;

    if (!last) {
        uint4 o;
        o.x = (unsigned)f2bf(n0) | ((unsigned)f2bf(n1) << 16);
        o.y = (unsigned)f2bf(n2) | ((unsigned)f2bf(n3) << 16);
        o.z = (unsigned)f2bf(n4) | ((unsigned)f2bf(n5) << 16);
        o.w = (unsigned)f2bf(n6) | ((unsigned)f2bf(n7) << 16);
        *reinterpret_cast<uint4*>(g_out + base) = o;
    } else {
        float th0 = theta[0], th1 = theta[1], th2 = theta[2], th3 = theta[3], th4 = theta[4];
        uint4 qf = *reinterpret_cast<const uint4*>(f16 + base);
        uint4 q1 = *reinterpret_cast<const uint4*>(t1 + base);
        uint4 q2 = *reinterpret_cast<const uint4*>(t2 + base);
        float4 h0, h1;
        h0.x = th0*bfl(qf.x) + th1*bfl(q1.x) + th2*bfl(q2.x) + th3*c0 + th4*n0;
        h0.y = th0*bfh(qf.x) + th1*bfh(q1.x) + th2*bfh(q2.x) + th3*c1 + th4*n1;
        h0.z = th0*bfl(qf.y) + th1*bfl(q1.y) + th2*bfl(q2.y) + th3*c2 + th4*n2;
        h0.w = th0*bfh(qf.y) + th1*bfh(q1.y) + th2*bfh(q2.y) + th3*c3 + th4*n3;
        h1.x = th0*bfl(qf.z) + th1*bfl(q1.z) + th2*bfl(q2.z) + th3*c4 + th4*n4;
        h1.y = th0*bfh(qf.z) + th1*bfh(q1.z) + th2*bfh(q2.z) + th3*c5 + th4*n5;
        h1.z = th0*bfl(qf.w) + th1*bfl(q1.w) + th2*bfl(q2.w) + th3*c6 + th4*n6;
        h1.w = th0*bfh(qf.w) + th1*bfh(q1.w) + th2*bfh(q2.w) + th3*c7 + th4*n7;
        *reinterpret_cast<float4*>(h + base) = h0;
        *reinterpret_cast<float4*>(h + base + 4) = h1;
    }
}

extern "C" void kernel_launch(void* const* d_in, const int* in_sizes, int n_in,
                              void* d_out, int out_size, void* d_ws, size_t ws_size,
                              hipStream_t stream) {
    const float* feat  = (const float*)d_in[0];
    const float* vals  = (const float*)d_in[1];
    const float* theta = (const float*)d_in[2];
    const int*   row   = (const int*)d_in[3];
    const int*   col   = (const int*)d_in[4];
    float* h = (float*)d_out;

    char* ws = (char*)d_ws;
    size_t off = 0;
    auto alloc = [&](size_t bytes) { void* p = ws + off; off = (off + bytes + 63) & ~(size_t)63; return p; };
    unsigned short* feat16 = (unsigned short*)alloc((size_t)N_NODES * D_FEAT * sizeof(short));
    unsigned short* T1 = (unsigned short*)alloc((size_t)N_NODES * D_FEAT * sizeof(short));
    unsigned short* T2 = (unsigned short*)alloc((size_t)N_NODES * D_FEAT * sizeof(short));
    unsigned short* T3 = (unsigned short*)alloc((size_t)N_NODES * D_FEAT * sizeof(short));
    int4*  prr      = (int4*)alloc((size_t)N_NODES * sizeof(int4));
    int*   win_cursor = (int*)alloc((size_t)NWIN * WPAD * sizeof(int));
    uint2* pile     = (uint2*)alloc((size_t)NWIN * CAP * sizeof(uint2));                // 16.8 MB
    unsigned int* cv = (unsigned int*)alloc((size_t)NWIN * CAP * sizeof(unsigned int)); // 8.4 MB

    const int blk = 256;
    const int n4 = N_NODES * D_FEAT / 4;

    // ---- setup + CSR build; finesort + degree-perm fused with spmm pass 1 ----
    cursor_kernel<<<(NWIN + 255) / 256, 256, 0, stream>>>(win_cursor);
    bucket_kernel<<<EB_NB, EB_BS, 0, stream>>>(row, col, vals, win_cursor, pile, feat, feat16, n4);
    finesort_spmm1_kernel<<<NWIN, 1024, 0, stream>>>(pile, win_cursor, cv, prr, feat16, T1);

    // ---- remaining 3 bf16-state polynomial steps; h fused into the last ----
    const int sgrid = (N_NODES * 4 + blk - 1) / blk;
    spmm_kernel<<<sgrid, blk, 0, stream>>>(prr, cv, T1, T2, nullptr, nullptr, nullptr, theta, nullptr, 0);
    spmm_kernel<<<sgrid, blk, 0, stream>>>(prr, cv, T2, T3, nullptr, nullptr, nullptr, theta, nullptr, 0);
    spmm_kernel<<<sgrid, blk, 0, stream>>>(prr, cv, T3, nullptr, feat16, T1, T2, theta, h, 1);
}

// Round 16
// 129.032 us; speedup vs baseline: 1.1087x; 1.1087x over previous
//
#include <hip/hip_runtime.h>

#define N_NODES 100000
#define N_EDGES 1600000
#define D_FEAT 32

#define NWIN 512
#define RPW  ((N_NODES + NWIN - 1) / NWIN)   // 196 rows per window (fits in 8 bits)
#define WPAD 16                               // pad window cursors to 64B lines
#define CAP  4096                             // per-window capacity (mean 3125, +17 sigma)

// pack: col (17 bits) << 15 | val_fix (15 bits), val_fix = round(val * 2^19)
#define VAL_SCALE 524288.0f
#define VAL_INV   (1.0f / 524288.0f)

// edge-block geometry for bucket
#define EB_BS  256
#define EB_EPT 16
#define EB_EPB (EB_BS * EB_EPT)               // 4096 edges per block
#define EB_NB  ((N_EDGES + EB_EPB - 1) / EB_EPB)  // 391 blocks

__device__ __forceinline__ unsigned short f2bf(float f) {
    unsigned u = __float_as_uint(f);
    unsigned r = u + 0x7fffu + ((u >> 16) & 1u);   // round-to-nearest-even
    return (unsigned short)(r >> 16);
}
__device__ __forceinline__ float bfl(unsigned u) { return __uint_as_float(u << 16); }
__device__ __forceinline__ float bfh(unsigned u) { return __uint_as_float(u & 0xffff0000u); }

// ---------------- tiny cursor init ----------------

__global__ __launch_bounds__(256) void cursor_kernel(int* __restrict__ win_cursor) {
    int i = blockIdx.x * 256 + threadIdx.x;
    if (i < NWIN) win_cursor[i * WPAD] = i * CAP;
}

// ---------------- counting sort into per-window piles (once per call) ----------------

// LDS-staged bucket: block-sort 4096 edges by window in LDS, then copy out
// linearly so global stores coalesce into full-line runs per window.
// Tail: grid-stride feat->bf16 conversion (consumed two kernels later).
__global__ __launch_bounds__(EB_BS) void bucket_kernel(const int* __restrict__ row,
                                                       const int* __restrict__ col,
                                                       const float* __restrict__ vals,
                                                       int* __restrict__ win_cursor,
                                                       uint2* __restrict__ pile,
                                                       const float* __restrict__ feat,
                                                       unsigned short* __restrict__ feat16,
                                                       int n4) {
    __shared__ int wcnt[NWIN];     // histogram, then reused as placement cursor
    __shared__ int lbase[NWIN];    // block-local exclusive scan
    __shared__ int wbase[NWIN];    // global reserved base per window
    __shared__ int ps[EB_BS];      // pair-sum scan workspace
    __shared__ uint2 stage[EB_EPB];// 32 KB staging
    int t = threadIdx.x;
    for (int i = t; i < NWIN; i += EB_BS) wcnt[i] = 0;
    __syncthreads();

    int base = blockIdx.x * EB_EPB;
    unsigned pk_[EB_EPT];   // packed {col|val}
    int wr_[EB_EPT];        // (w<<8) | local_row, or -1
#pragma unroll
    for (int i = 0; i < EB_EPT; ++i) {
        int e = base + i * EB_BS + t;
        if (e < N_EDGES) {
            int r = row[e];
            int w = r / RPW;
            unsigned fx = (unsigned)__float2int_rn(vals[e] * VAL_SCALE);
            if (fx > 0x7FFFu) fx = 0x7FFFu;
            pk_[i] = ((unsigned)col[e] << 15) | fx;
            wr_[i] = (w << 8) | (r - w * RPW);
            atomicAdd(&wcnt[w], 1);
        } else wr_[i] = -1;
    }
    __syncthreads();

    // exclusive scan of wcnt[0..511] -> lbase (2 elements per thread)
    int c0 = wcnt[2 * t], c1 = wcnt[2 * t + 1];
    ps[t] = c0 + c1;
    __syncthreads();
    for (int off = 1; off < EB_BS; off <<= 1) {
        int u = (t >= off) ? ps[t - off] : 0;
        __syncthreads();
        ps[t] += u;
        __syncthreads();
    }
    int pex = ps[t] - (c0 + c1);
    lbase[2 * t]     = pex;
    lbase[2 * t + 1] = pex + c0;
    __syncthreads();

    // reserve global space per window; reset cursor to local base
    for (int i = t; i < NWIN; i += EB_BS) {
        int cw = wcnt[i];
        wbase[i] = cw ? atomicAdd(&win_cursor[i * WPAD], cw) : 0;
    }
    __syncthreads();
    for (int i = t; i < NWIN; i += EB_BS) wcnt[i] = lbase[i];
    __syncthreads();

    // place edges into LDS staging, sorted by window
#pragma unroll
    for (int i = 0; i < EB_EPT; ++i) {
        if (wr_[i] < 0) continue;
        int w = wr_[i] >> 8;
        int loc = atomicAdd(&wcnt[w], 1);
        stage[loc] = make_uint2(pk_[i], (unsigned)wr_[i]);
    }
    __syncthreads();

    // linear LDS -> global copy: consecutive i in one window hit consecutive
    // pile slots -> coalesced full-line stores (except at window boundaries)
    int nedge = N_EDGES - base; if (nedge > EB_EPB) nedge = EB_EPB;
    for (int i = t; i < nedge; i += EB_BS) {
        uint2 ed = stage[i];
        int w = ed.y >> 8;
        int pos = wbase[w] + (i - lbase[w]);
        pile[pos] = make_uint2(ed.x, ed.y & 0xFFu);
    }

    // tail: feat -> bf16 mirror (grid-stride)
    for (int i = blockIdx.x * EB_BS + t; i < n4; i += EB_NB * EB_BS) {
        float4 f = reinterpret_cast<const float4*>(feat)[i];
        ushort4 o;
        o.x = f2bf(f.x); o.y = f2bf(f.y); o.z = f2bf(f.z); o.w = f2bf(f.w);
        reinterpret_cast<ushort4*>(feat16)[i] = o;
    }
}

// ---------------- gather macros ----------------

#define GATH(qq, pp) \
    uint4 qq = *(reinterpret_cast<const uint4*>(gsrc + (size_t)((pp) >> 15) * D_FEAT) + c)
#define ACC(qq, vv) \
    a0 += (vv) * bfl(qq.x); a1 += (vv) * bfh(qq.x); a2 += (vv) * bfl(qq.y); a3 += (vv) * bfh(qq.y); \
    a4 += (vv) * bfl(qq.z); a5 += (vv) * bfh(qq.z); a6 += (vv) * bfl(qq.w); a7 += (vv) * bfh(qq.w)

// ---------------- merged finesort + spmm pass 1 (one 1024-thread block per window) ----------------
// Bins = local_row*4 + col_quadrant: each row's CSR range is contiguous but
// internally grouped by source quadrant (1.6 MB -> per-XCD-L2-resident), so the
// co-resident grid sweeps 4 cache phases instead of thrashing a 6.4 MB source.
// Phase 1: histogram -> 1024-wide scan -> row_rng (global, passes 2-4)
// Phase 2: scatter pile into (row, quad) order: LDS cvl + global cv
// Phase 3: pull-spmm pass 1 from the LDS edge list.
__global__ __launch_bounds__(1024) void finesort_spmm1_kernel(const uint2* __restrict__ pile,
                               const int* __restrict__ win_cursor,
                               unsigned int* __restrict__ cvout,
                               int2* __restrict__ row_rng,
                               const unsigned short* __restrict__ gsrc,
                               unsigned short* __restrict__ g_out) {
    __shared__ int cnt[1024];     // bins: local_row*4 + quad (784 used)
    __shared__ int incl[1024];
    __shared__ int cur[1024];
    __shared__ int ex[1024];
    __shared__ unsigned cvl[CAP];            // 16 KB
    int w = blockIdx.x, t = threadIdx.x;
    int rbeg = w * RPW;
    int rcnt = N_NODES - rbeg;
    if (rcnt > RPW) rcnt = RPW;
    if (rcnt < 0) rcnt = 0;
    int pbeg = w * CAP;
    int pend = win_cursor[w * WPAD];
    cnt[t] = 0;
    __syncthreads();
    for (int i = pbeg + t; i < pend; i += 1024) {
        uint2 ed = pile[i];
        int quad = (int)((ed.x >> 15) / 25000u);          // 0..3
        atomicAdd(&cnt[ed.y * 4 + quad], 1);
    }
    __syncthreads();
    int v = cnt[t];
    incl[t] = v;
    __syncthreads();
    for (int off = 1; off < 1024; off <<= 1) {
        int u = (t >= off) ? incl[t - off] : 0;
        __syncthreads();
        incl[t] += u;
        __syncthreads();
    }
    ex[t] = incl[t] - v;
    cur[t] = ex[t];
    __syncthreads();
    if (t < rcnt) row_rng[rbeg + t] = make_int2(pbeg + ex[t * 4], pbeg + incl[t * 4 + 3]);
    for (int i = pbeg + t; i < pend; i += 1024) {
        uint2 ed = pile[i];
        int quad = (int)((ed.x >> 15) / 25000u);
        int pos = atomicAdd(&cur[ed.y * 4 + quad], 1);
        cvl[pos] = ed.x;
        cvout[pbeg + pos] = ed.x;
    }
    __syncthreads();

    // ---- spmm pass 1 for this window's rows, edges from LDS ----
    if (t < rcnt * 4) {
        int lr = t >> 2, c = t & 3;
        int e = ex[lr * 4];
        int end = incl[lr * 4 + 3];
        float a0=0.f,a1=0.f,a2=0.f,a3=0.f,a4=0.f,a5=0.f,a6=0.f,a7=0.f;
        for (; e + 4 <= end; e += 4) {
            unsigned p0 = cvl[e + 0], p1 = cvl[e + 1], p2 = cvl[e + 2], p3 = cvl[e + 3];
            GATH(q0, p0); GATH(q1, p1); GATH(q2, p2); GATH(q3, p3);
            float v0 = (float)(p0 & 0x7FFFu) * VAL_INV;
            float v1 = (float)(p1 & 0x7FFFu) * VAL_INV;
            float v2 = (float)(p2 & 0x7FFFu) * VAL_INV;
            float v3 = (float)(p3 & 0x7FFFu) * VAL_INV;
            ACC(q0, v0); ACC(q1, v1); ACC(q2, v2); ACC(q3, v3);
        }
        for (; e < end; ++e) {
            unsigned p = cvl[e];
            float vv = (float)(p & 0x7FFFu) * VAL_INV;
            GATH(q, p);
            ACC(q, vv);
        }
        size_t base = (size_t)(rbeg + lr) * D_FEAT + c * 8;
        uint4 qi = *reinterpret_cast<const uint4*>(gsrc + base);
        float c0=bfl(qi.x), c1=bfh(qi.x), c2=bfl(qi.y), c3=bfh(qi.y);
        float c4=bfl(qi.z), c5=bfh(qi.z), c6=bfl(qi.w), c7=bfh(qi.w);
        uint4 o;
        o.x = (unsigned)f2bf(c0 - a0) | ((unsigned)f2bf(c1 - a1) << 16);
        o.y = (unsigned)f2bf(c2 - a2) | ((unsigned)f2bf(c3 - a3) << 16);
        o.z = (unsigned)f2bf(c4 - a4) | ((unsigned)f2bf(c5 - a5) << 16);
        o.w = (unsigned)f2bf(c6 - a6) | ((unsigned)f2bf(c7 - a7) << 16);
        *reinterpret_cast<uint4*>(g_out + base) = o;
    }
}

// ---------------- polynomial steps 2..4 (flat pull, consecutive rows) ----------------

// Uniform bf16-state step: cn = gsrc[r] - sum_e val * gsrc[col]  (f32 accumulate)
//   last==0: g_out[r] = bf16(cn)
//   last==1: h[r] = th0*f16[r] + th1*t1[r] + th2*t2[r] + th3*gsrc[r] + th4*cn
// 4 lanes per row (uint4 = 8 bf16 each); edge loop pipelined 8-deep for MLP.
__global__ __launch_bounds__(256) void spmm_kernel(const int2* __restrict__ row_rng,
                               const unsigned int* __restrict__ cv,
                               const unsigned short* __restrict__ gsrc,
                               unsigned short* __restrict__ g_out,
                               const unsigned short* __restrict__ f16,
                               const unsigned short* __restrict__ t1,
                               const unsigned short* __restrict__ t2,
                               const float* __restrict__ theta,
                               float* __restrict__ h,
                               int last) {
    int tid = blockIdx.x * blockDim.x + threadIdx.x;
    int r = tid >> 2;
    int c = tid & 3;
    if (r >= N_NODES) return;
    int2 rng = row_rng[r];
    int e = rng.x, end = rng.y;
    float a0=0.f,a1=0.f,a2=0.f,a3=0.f,a4=0.f,a5=0.f,a6=0.f,a7=0.f;

    for (; e + 8 <= end; e += 8) {
        unsigned p0 = cv[e + 0], p1 = cv[e + 1], p2 = cv[e + 2], p3 = cv[e + 3];
        unsigned p4 = cv[e + 4], p5 = cv[e + 5], p6 = cv[e + 6], p7 = cv[e + 7];
        GATH(q0, p0); GATH(q1, p1); GATH(q2, p2); GATH(q3, p3);
        GATH(q4, p4); GATH(q5, p5); GATH(q6, p6); GATH(q7, p7);
        float v0 = (float)(p0 & 0x7FFFu) * VAL_INV;
        float v1 = (float)(p1 & 0x7FFFu) * VAL_INV;
        float v2 = (float)(p2 & 0x7FFFu) * VAL_INV;
        float v3 = (float)(p3 & 0x7FFFu) * VAL_INV;
        float v4 = (float)(p4 & 0x7FFFu) * VAL_INV;
        float v5 = (float)(p5 & 0x7FFFu) * VAL_INV;
        float v6 = (float)(p6 & 0x7FFFu) * VAL_INV;
        float v7 = (float)(p7 & 0x7FFFu) * VAL_INV;
        ACC(q0, v0); ACC(q1, v1); ACC(q2, v2); ACC(q3, v3);
        ACC(q4, v4); ACC(q5, v5); ACC(q6, v6); ACC(q7, v7);
    }
    for (; e + 4 <= end; e += 4) {
        unsigned p0 = cv[e + 0], p1 = cv[e + 1], p2 = cv[e + 2], p3 = cv[e + 3];
        GATH(q0, p0); GATH(q1, p1); GATH(q2, p2); GATH(q3, p3);
        float v0 = (float)(p0 & 0x7FFFu) * VAL_INV;
        float v1 = (float)(p1 & 0x7FFFu) * VAL_INV;
        float v2 = (float)(p2 & 0x7FFFu) * VAL_INV;
        float v3 = (float)(p3 & 0x7FFFu) * VAL_INV;
        ACC(q0, v0); ACC(q1, v1); ACC(q2, v2); ACC(q3, v3);
    }
    for (; e < end; ++e) {
        unsigned p = cv[e];
        float v = (float)(p & 0x7FFFu) * VAL_INV;
        GATH(q, p);
        ACC(q, v);
    }

    size_t base = (size_t)r * D_FEAT + c * 8;
    uint4 qi = *reinterpret_cast<const uint4*>(gsrc + base);   // identity (bf16, hot)
    float c0=bfl(qi.x), c1=bfh(qi.x), c2=bfl(qi.y), c3=bfh(qi.y);
    float c4=bfl(qi.z), c5=bfh(qi.z), c6=bfl(qi.w), c7=bfh(qi.w);
    float n0=c0-a0, n1=c1-a1, n2=c2-a2, n3=c3-a3, n4=c4-a4, n5=c5-a5, n6=c6-a6, n7=c7-a7;

    if (!last) {
        uint4 o;
        o.x = (unsigned)f2bf(n0) | ((unsigned)f2bf(n1) << 16);
        o.y = (unsigned)f2bf(n2) | ((unsigned)f2bf(n3) << 16);
        o.z = (unsigned)f2bf(n4) | ((unsigned)f2bf(n5) << 16);
        o.w = (unsigned)f2bf(n6) | ((unsigned)f2bf(n7) << 16);
        *reinterpret_cast<uint4*>(g_out + base) = o;
    } else {
        float th0 = theta[0], th1 = theta[1], th2 = theta[2], th3 = theta[3], th4 = theta[4];
        uint4 qf = *reinterpret_cast<const uint4*>(f16 + base);
        uint4 q1 = *reinterpret_cast<const uint4*>(t1 + base);
        uint4 q2 = *reinterpret_cast<const uint4*>(t2 + base);
        float4 h0, h1;
        h0.x = th0*bfl(qf.x) + th1*bfl(q1.x) + th2*bfl(q2.x) + th3*c0 + th4*n0;
        h0.y = th0*bfh(qf.x) + th1*bfh(q1.x) + th2*bfh(q2.x) + th3*c1 + th4*n1;
        h0.z = th0*bfl(qf.y) + th1*bfl(q1.y) + th2*bfl(q2.y) + th3*c2 + th4*n2;
        h0.w = th0*bfh(qf.y) + th1*bfh(q1.y) + th2*bfh(q2.y) + th3*c3 + th4*n3;
        h1.x = th0*bfl(qf.z) + th1*bfl(q1.z) + th2*bfl(q2.z) + th3*c4 + th4*n4;
        h1.y = th0*bfh(qf.z) + th1*bfh(q1.z) + th2*bfh(q2.z) + th3*c5 + th4*n5;
        h1.z = th0*bfl(qf.w) + th1*bfl(q1.w) + th2*bfl(q2.w) + th3*c6 + th4*n6;
        h1.w = th0*bfh(qf.w) + th1*bfh(q1.w) + th2*bfh(q2.w) + th3*c7 + th4*n7;
        *reinterpret_cast<float4*>(h + base) = h0;
        *reinterpret_cast<float4*>(h + base + 4) = h1;
    }
}

extern "C" void kernel_launch(void* const* d_in, const int* in_sizes, int n_in,
                              void* d_out, int out_size, void* d_ws, size_t ws_size,
                              hipStream_t stream) {
    const float* feat  = (const float*)d_in[0];
    const float* vals  = (const float*)d_in[1];
    const float* theta = (const float*)d_in[2];
    const int*   row   = (const int*)d_in[3];
    const int*   col   = (const int*)d_in[4];
    float* h = (float*)d_out;

    char* ws = (char*)d_ws;
    size_t off = 0;
    auto alloc = [&](size_t bytes) { void* p = ws + off; off = (off + bytes + 63) & ~(size_t)63; return p; };
    unsigned short* feat16 = (unsigned short*)alloc((size_t)N_NODES * D_FEAT * sizeof(short));
    unsigned short* T1 = (unsigned short*)alloc((size_t)N_NODES * D_FEAT * sizeof(short));
    unsigned short* T2 = (unsigned short*)alloc((size_t)N_NODES * D_FEAT * sizeof(short));
    unsigned short* T3 = (unsigned short*)alloc((size_t)N_NODES * D_FEAT * sizeof(short));
    int2*  row_rng  = (int2*)alloc((size_t)N_NODES * sizeof(int2));
    int*   win_cursor = (int*)alloc((size_t)NWIN * WPAD * sizeof(int));
    uint2* pile     = (uint2*)alloc((size_t)NWIN * CAP * sizeof(uint2));                // 16.8 MB
    unsigned int* cv = (unsigned int*)alloc((size_t)NWIN * CAP * sizeof(unsigned int)); // 8.4 MB

    const int blk = 256;
    const int n4 = N_NODES * D_FEAT / 4;

    // ---- setup + CSR build; finesort (colquad-grouped) fused with spmm pass 1 ----
    cursor_kernel<<<(NWIN + 255) / 256, 256, 0, stream>>>(win_cursor);
    bucket_kernel<<<EB_NB, EB_BS, 0, stream>>>(row, col, vals, win_cursor, pile, feat, feat16, n4);
    finesort_spmm1_kernel<<<NWIN, 1024, 0, stream>>>(pile, win_cursor, cv, row_rng, feat16, T1);

    // ---- remaining 3 bf16-state polynomial steps; h fused into the last ----
    const int sgrid = (N_NODES * 4 + blk - 1) / blk;
    spmm_kernel<<<sgrid, blk, 0, stream>>>(row_rng, cv, T1, T2, nullptr, nullptr, nullptr, theta, nullptr, 0);
    spmm_kernel<<<sgrid, blk, 0, stream>>>(row_rng, cv, T2, T3, nullptr, nullptr, nullptr, theta, nullptr, 0);
    spmm_kernel<<<sgrid, blk, 0, stream>>>(row_rng, cv, T3, nullptr, feat16, T1, T2, theta, h, 1);
}

// Round 17
// 128.348 us; speedup vs baseline: 1.1146x; 1.0053x over previous
//
#include <hip/hip_runtime.h>

#define N_NODES 100000
#define N_EDGES 1600000
#define D_FEAT 32

#define NWIN 512
#define RPW  ((N_NODES + NWIN - 1) / NWIN)   // 196 rows per window (fits in 8 bits)
#define WPAD 16                               // pad window cursors to 64B lines
#define CAP  4096                             // per-window capacity (mean 3125, +17 sigma)

#define NOCT 8                                // column octants (source phase = 0.8 MB, L2-resident)
#define OCTDIV 12500u                         // col / 12500 -> 0..7
#define NBINS (RPW * NOCT)                    // 1568 bins per window
#define NBPAD 2048                            // padded bin count (2 bins per thread @ 1024)

// pack: col (17 bits) << 15 | val_fix (15 bits), val_fix = round(val * 2^19)
#define VAL_SCALE 524288.0f
#define VAL_INV   (1.0f / 524288.0f)

// edge-block geometry for bucket
#define EB_BS  256
#define EB_EPT 16
#define EB_EPB (EB_BS * EB_EPT)               // 4096 edges per block
#define EB_NB  ((N_EDGES + EB_EPB - 1) / EB_EPB)  // 391 blocks

__device__ __forceinline__ unsigned short f2bf(float f) {
    unsigned u = __float_as_uint(f);
    unsigned r = u + 0x7fffu + ((u >> 16) & 1u);   // round-to-nearest-even
    return (unsigned short)(r >> 16);
}
__device__ __forceinline__ float bfl(unsigned u) { return __uint_as_float(u << 16); }
__device__ __forceinline__ float bfh(unsigned u) { return __uint_as_float(u & 0xffff0000u); }

// ---------------- tiny cursor init ----------------

__global__ __launch_bounds__(256) void cursor_kernel(int* __restrict__ win_cursor) {
    int i = blockIdx.x * 256 + threadIdx.x;
    if (i < NWIN) win_cursor[i * WPAD] = i * CAP;
}

// ---------------- counting sort into per-window piles (once per call) ----------------

// LDS-staged bucket: block-sort 4096 edges by window in LDS, then copy out
// linearly so global stores coalesce into full-line runs per window.
// Tail: grid-stride feat->bf16 conversion (consumed two kernels later).
__global__ __launch_bounds__(EB_BS) void bucket_kernel(const int* __restrict__ row,
                                                       const int* __restrict__ col,
                                                       const float* __restrict__ vals,
                                                       int* __restrict__ win_cursor,
                                                       uint2* __restrict__ pile,
                                                       const float* __restrict__ feat,
                                                       unsigned short* __restrict__ feat16,
                                                       int n4) {
    __shared__ int wcnt[NWIN];     // histogram, then reused as placement cursor
    __shared__ int lbase[NWIN];    // block-local exclusive scan
    __shared__ int wbase[NWIN];    // global reserved base per window
    __shared__ int ps[EB_BS];      // pair-sum scan workspace
    __shared__ uint2 stage[EB_EPB];// 32 KB staging
    int t = threadIdx.x;
    for (int i = t; i < NWIN; i += EB_BS) wcnt[i] = 0;
    __syncthreads();

    int base = blockIdx.x * EB_EPB;
    unsigned pk_[EB_EPT];   // packed {col|val}
    int wr_[EB_EPT];        // (w<<8) | local_row, or -1
#pragma unroll
    for (int i = 0; i < EB_EPT; ++i) {
        int e = base + i * EB_BS + t;
        if (e < N_EDGES) {
            int r = row[e];
            int w = r / RPW;
            unsigned fx = (unsigned)__float2int_rn(vals[e] * VAL_SCALE);
            if (fx > 0x7FFFu) fx = 0x7FFFu;
            pk_[i] = ((unsigned)col[e] << 15) | fx;
            wr_[i] = (w << 8) | (r - w * RPW);
            atomicAdd(&wcnt[w], 1);
        } else wr_[i] = -1;
    }
    __syncthreads();

    // exclusive scan of wcnt[0..511] -> lbase (2 elements per thread)
    int c0 = wcnt[2 * t], c1 = wcnt[2 * t + 1];
    ps[t] = c0 + c1;
    __syncthreads();
    for (int off = 1; off < EB_BS; off <<= 1) {
        int u = (t >= off) ? ps[t - off] : 0;
        __syncthreads();
        ps[t] += u;
        __syncthreads();
    }
    int pex = ps[t] - (c0 + c1);
    lbase[2 * t]     = pex;
    lbase[2 * t + 1] = pex + c0;
    __syncthreads();

    // reserve global space per window; reset cursor to local base
    for (int i = t; i < NWIN; i += EB_BS) {
        int cw = wcnt[i];
        wbase[i] = cw ? atomicAdd(&win_cursor[i * WPAD], cw) : 0;
    }
    __syncthreads();
    for (int i = t; i < NWIN; i += EB_BS) wcnt[i] = lbase[i];
    __syncthreads();

    // place edges into LDS staging, sorted by window
#pragma unroll
    for (int i = 0; i < EB_EPT; ++i) {
        if (wr_[i] < 0) continue;
        int w = wr_[i] >> 8;
        int loc = atomicAdd(&wcnt[w], 1);
        stage[loc] = make_uint2(pk_[i], (unsigned)wr_[i]);
    }
    __syncthreads();

    // linear LDS -> global copy: consecutive i in one window hit consecutive
    // pile slots -> coalesced full-line stores (except at window boundaries)
    int nedge = N_EDGES - base; if (nedge > EB_EPB) nedge = EB_EPB;
    for (int i = t; i < nedge; i += EB_BS) {
        uint2 ed = stage[i];
        int w = ed.y >> 8;
        int pos = wbase[w] + (i - lbase[w]);
        pile[pos] = make_uint2(ed.x, ed.y & 0xFFu);
    }

    // tail: feat -> bf16 mirror (grid-stride)
    for (int i = blockIdx.x * EB_BS + t; i < n4; i += EB_NB * EB_BS) {
        float4 f = reinterpret_cast<const float4*>(feat)[i];
        ushort4 o;
        o.x = f2bf(f.x); o.y = f2bf(f.y); o.z = f2bf(f.z); o.w = f2bf(f.w);
        reinterpret_cast<ushort4*>(feat16)[i] = o;
    }
}

// ---------------- gather macros ----------------

#define GATH(qq, pp) \
    uint4 qq = *(reinterpret_cast<const uint4*>(gsrc + (size_t)((pp) >> 15) * D_FEAT) + c)
#define ACC(qq, vv) \
    a0 += (vv) * bfl(qq.x); a1 += (vv) * bfh(qq.x); a2 += (vv) * bfl(qq.y); a3 += (vv) * bfh(qq.y); \
    a4 += (vv) * bfl(qq.z); a5 += (vv) * bfh(qq.z); a6 += (vv) * bfl(qq.w); a7 += (vv) * bfh(qq.w)

// ---------------- merged finesort + spmm pass 1 (one 1024-thread block per window) ----------------
// Bins = local_row*8 + col_octant: each row's CSR range is contiguous but
// internally grouped by source octant (0.8 MB -> comfortably per-XCD-L2-resident
// alongside the cv/identity/output streams), so the co-resident grid sweeps 8
// cache phases instead of thrashing a 6.4 MB source.
// Phase 1: histogram (1568 bins) -> 2-bin/thread scan -> row_rng (global)
// Phase 2: scatter pile into (row, oct) order: LDS cvl + global cv
// Phase 3: pull-spmm pass 1 from the LDS edge list.
__global__ __launch_bounds__(1024) void finesort_spmm1_kernel(const uint2* __restrict__ pile,
                               const int* __restrict__ win_cursor,
                               unsigned int* __restrict__ cvout,
                               int2* __restrict__ row_rng,
                               const unsigned short* __restrict__ gsrc,
                               unsigned short* __restrict__ g_out) {
    __shared__ int cnt[NBPAD];       // histogram -> cursor (8 KB)
    __shared__ int incl[NBPAD];      // inclusive scan (8 KB)
    __shared__ int ps[1024];         // pair-sum scan workspace (4 KB)
    __shared__ int rowbeg[RPW];      // per-row local range (0.8 KB)
    __shared__ int rowend[RPW];
    __shared__ unsigned cvl[CAP];    // 16 KB
    int w = blockIdx.x, t = threadIdx.x;
    int rbeg = w * RPW;
    int rcnt = N_NODES - rbeg;
    if (rcnt > RPW) rcnt = RPW;
    if (rcnt < 0) rcnt = 0;
    int pbeg = w * CAP;
    int pend = win_cursor[w * WPAD];
    cnt[t] = 0;
    cnt[t + 1024] = 0;
    __syncthreads();
    for (int i = pbeg + t; i < pend; i += 1024) {
        uint2 ed = pile[i];
        int oct = (int)((ed.x >> 15) / OCTDIV);           // 0..7
        atomicAdd(&cnt[ed.y * NOCT + oct], 1);
    }
    __syncthreads();
    // 2-bin-per-thread inclusive scan over NBPAD bins
    int b0 = cnt[2 * t], b1 = cnt[2 * t + 1];
    ps[t] = b0 + b1;
    __syncthreads();
    for (int off = 1; off < 1024; off <<= 1) {
        int u = (t >= off) ? ps[t - off] : 0;
        __syncthreads();
        ps[t] += u;
        __syncthreads();
    }
    int pex = ps[t] - (b0 + b1);
    incl[2 * t]     = pex + b0;
    incl[2 * t + 1] = pex + b0 + b1;
    __syncthreads();
    // per-row ranges (read cnt before it is converted to cursor)
    if (t < rcnt) {
        int beg = incl[t * NOCT] - cnt[t * NOCT];
        int end = incl[t * NOCT + NOCT - 1];
        rowbeg[t] = beg;
        rowend[t] = end;
        row_rng[rbeg + t] = make_int2(pbeg + beg, pbeg + end);
    }
    __syncthreads();
    // convert cnt -> exclusive cursor
    cnt[2 * t]     = incl[2 * t] - b0;
    cnt[2 * t + 1] = incl[2 * t + 1] - b1;
    __syncthreads();
    for (int i = pbeg + t; i < pend; i += 1024) {
        uint2 ed = pile[i];
        int oct = (int)((ed.x >> 15) / OCTDIV);
        int pos = atomicAdd(&cnt[ed.y * NOCT + oct], 1);
        cvl[pos] = ed.x;
        cvout[pbeg + pos] = ed.x;
    }
    __syncthreads();

    // ---- spmm pass 1 for this window's rows, edges from LDS ----
    if (t < rcnt * 4) {
        int lr = t >> 2, c = t & 3;
        int e = rowbeg[lr];
        int end = rowend[lr];
        float a0=0.f,a1=0.f,a2=0.f,a3=0.f,a4=0.f,a5=0.f,a6=0.f,a7=0.f;
        for (; e + 4 <= end; e += 4) {
            unsigned p0 = cvl[e + 0], p1 = cvl[e + 1], p2 = cvl[e + 2], p3 = cvl[e + 3];
            GATH(q0, p0); GATH(q1, p1); GATH(q2, p2); GATH(q3, p3);
            float v0 = (float)(p0 & 0x7FFFu) * VAL_INV;
            float v1 = (float)(p1 & 0x7FFFu) * VAL_INV;
            float v2 = (float)(p2 & 0x7FFFu) * VAL_INV;
            float v3 = (float)(p3 & 0x7FFFu) * VAL_INV;
            ACC(q0, v0); ACC(q1, v1); ACC(q2, v2); ACC(q3, v3);
        }
        for (; e < end; ++e) {
            unsigned p = cvl[e];
            float vv = (float)(p & 0x7FFFu) * VAL_INV;
            GATH(q, p);
            ACC(q, vv);
        }
        size_t base = (size_t)(rbeg + lr) * D_FEAT + c * 8;
        uint4 qi = *reinterpret_cast<const uint4*>(gsrc + base);
        float c0=bfl(qi.x), c1=bfh(qi.x), c2=bfl(qi.y), c3=bfh(qi.y);
        float c4=bfl(qi.z), c5=bfh(qi.z), c6=bfl(qi.w), c7=bfh(qi.w);
        uint4 o;
        o.x = (unsigned)f2bf(c0 - a0) | ((unsigned)f2bf(c1 - a1) << 16);
        o.y = (unsigned)f2bf(c2 - a2) | ((unsigned)f2bf(c3 - a3) << 16);
        o.z = (unsigned)f2bf(c4 - a4) | ((unsigned)f2bf(c5 - a5) << 16);
        o.w = (unsigned)f2bf(c6 - a6) | ((unsigned)f2bf(c7 - a7) << 16);
        *reinterpret_cast<uint4*>(g_out + base) = o;
    }
}

// ---------------- polynomial steps 2..4 (flat pull, consecutive rows) ----------------

// Uniform bf16-state step: cn = gsrc[r] - sum_e val * gsrc[col]  (f32 accumulate)
//   last==0: g_out[r] = bf16(cn)
//   last==1: h[r] = th0*f16[r] + th1*t1[r] + th2*t2[r] + th3*gsrc[r] + th4*cn
// 4 lanes per row (uint4 = 8 bf16 each); edge loop pipelined 8-deep for MLP.
__global__ __launch_bounds__(256) void spmm_kernel(const int2* __restrict__ row_rng,
                               const unsigned int* __restrict__ cv,
                               const unsigned short* __restrict__ gsrc,
                               unsigned short* __restrict__ g_out,
                               const unsigned short* __restrict__ f16,
                               const unsigned short* __restrict__ t1,
                               const unsigned short* __restrict__ t2,
                               const float* __restrict__ theta,
                               float* __restrict__ h,
                               int last) {
    int tid = blockIdx.x * blockDim.x + threadIdx.x;
    int r = tid >> 2;
    int c = tid & 3;
    if (r >= N_NODES) return;
    int2 rng = row_rng[r];
    int e = rng.x, end = rng.y;
    float a0=0.f,a1=0.f,a2=0.f,a3=0.f,a4=0.f,a5=0.f,a6=0.f,a7=0.f;

    for (; e + 8 <= end; e += 8) {
        unsigned p0 = cv[e + 0], p1 = cv[e + 1], p2 = cv[e + 2], p3 = cv[e + 3];
        unsigned p4 = cv[e + 4], p5 = cv[e + 5], p6 = cv[e + 6], p7 = cv[e + 7];
        GATH(q0, p0); GATH(q1, p1); GATH(q2, p2); GATH(q3, p3);
        GATH(q4, p4); GATH(q5, p5); GATH(q6, p6); GATH(q7, p7);
        float v0 = (float)(p0 & 0x7FFFu) * VAL_INV;
        float v1 = (float)(p1 & 0x7FFFu) * VAL_INV;
        float v2 = (float)(p2 & 0x7FFFu) * VAL_INV;
        float v3 = (float)(p3 & 0x7FFFu) * VAL_INV;
        float v4 = (float)(p4 & 0x7FFFu) * VAL_INV;
        float v5 = (float)(p5 & 0x7FFFu) * VAL_INV;
        float v6 = (float)(p6 & 0x7FFFu) * VAL_INV;
        float v7 = (float)(p7 & 0x7FFFu) * VAL_INV;
        ACC(q0, v0); ACC(q1, v1); ACC(q2, v2); ACC(q3, v3);
        ACC(q4, v4); ACC(q5, v5); ACC(q6, v6); ACC(q7, v7);
    }
    for (; e + 4 <= end; e += 4) {
        unsigned p0 = cv[e + 0], p1 = cv[e + 1], p2 = cv[e + 2], p3 = cv[e + 3];
        GATH(q0, p0); GATH(q1, p1); GATH(q2, p2); GATH(q3, p3);
        float v0 = (float)(p0 & 0x7FFFu) * VAL_INV;
        float v1 = (float)(p1 & 0x7FFFu) * VAL_INV;
        float v2 = (float)(p2 & 0x7FFFu) * VAL_INV;
        float v3 = (float)(p3 & 0x7FFFu) * VAL_INV;
        ACC(q0, v0); ACC(q1, v1); ACC(q2, v2); ACC(q3, v3);
    }
    for (; e < end; ++e) {
        unsigned p = cv[e];
        float v = (float)(p & 0x7FFFu) * VAL_INV;
        GATH(q, p);
        ACC(q, v);
    }

    size_t base = (size_t)r * D_FEAT + c * 8;
    uint4 qi = *reinterpret_cast<const uint4*>(gsrc + base);   // identity (bf16, hot)
    float c0=bfl(qi.x), c1=bfh(qi.x), c2=bfl(qi.y), c3=bfh(qi.y);
    float c4=bfl(qi.z), c5=bfh(qi.z), c6=bfl(qi.w), c7=bfh(qi.w);
    float n0=c0-a0, n1=c1-a1, n2=c2-a2, n3=c3-a3, n4=c4-a4, n5=c5-a5, n6=c6-a6, n7=c7-a7;

    if (!last) {
        uint4 o;
        o.x = (unsigned)f2bf(n0) | ((unsigned)f2bf(n1) << 16);
        o.y = (unsigned)f2bf(n2) | ((unsigned)f2bf(n3) << 16);
        o.z = (unsigned)f2bf(n4) | ((unsigned)f2bf(n5) << 16);
        o.w = (unsigned)f2bf(n6) | ((unsigned)f2bf(n7) << 16);
        *reinterpret_cast<uint4*>(g_out + base) = o;
    } else {
        float th0 = theta[0], th1 = theta[1], th2 = theta[2], th3 = theta[3], th4 = theta[4];
        uint4 qf = *reinterpret_cast<const uint4*>(f16 + base);
        uint4 q1 = *reinterpret_cast<const uint4*>(t1 + base);
        uint4 q2 = *reinterpret_cast<const uint4*>(t2 + base);
        float4 h0, h1;
        h0.x = th0*bfl(qf.x) + th1*bfl(q1.x) + th2*bfl(q2.x) + th3*c0 + th4*n0;
        h0.y = th0*bfh(qf.x) + th1*bfh(q1.x) + th2*bfh(q2.x) + th3*c1 + th4*n1;
        h0.z = th0*bfl(qf.y) + th1*bfl(q1.y) + th2*bfl(q2.y) + th3*c2 + th4*n2;
        h0.w = th0*bfh(qf.y) + th1*bfh(q1.y) + th2*bfh(q2.y) + th3*c3 + th4*n3;
        h1.x = th0*bfl(qf.z) + th1*bfl(q1.z) + th2*bfl(q2.z) + th3*c4 + th4*n4;
        h1.y = th0*bfh(qf.z) + th1*bfh(q1.z) + th2*bfh(q2.z) + th3*c5 + th4*n5;
        h1.z = th0*bfl(qf.w) + th1*bfl(q1.w) + th2*bfl(q2.w) + th3*c6 + th4*n6;
        h1.w = th0*bfh(qf.w) + th1*bfh(q1.w) + th2*bfh(q2.w) + th3*c7 + th4*n7;
        *reinterpret_cast<float4*>(h + base) = h0;
        *reinterpret_cast<float4*>(h + base + 4) = h1;
    }
}

extern "C" void kernel_launch(void* const* d_in, const int* in_sizes, int n_in,
                              void* d_out, int out_size, void* d_ws, size_t ws_size,
                              hipStream_t stream) {
    const float* feat  = (const float*)d_in[0];
    const float* vals  = (const float*)d_in[1];
    const float* theta = (const float*)d_in[2];
    const int*   row   = (const int*)d_in[3];
    const int*   col   = (const int*)d_in[4];
    float* h = (float*)d_out;

    char* ws = (char*)d_ws;
    size_t off = 0;
    auto alloc = [&](size_t bytes) { void* p = ws + off; off = (off + bytes + 63) & ~(size_t)63; return p; };
    unsigned short* feat16 = (unsigned short*)alloc((size_t)N_NODES * D_FEAT * sizeof(short));
    unsigned short* T1 = (unsigned short*)alloc((size_t)N_NODES * D_FEAT * sizeof(short));
    unsigned short* T2 = (unsigned short*)alloc((size_t)N_NODES * D_FEAT * sizeof(short));
    unsigned short* T3 = (unsigned short*)alloc((size_t)N_NODES * D_FEAT * sizeof(short));
    int2*  row_rng  = (int2*)alloc((size_t)N_NODES * sizeof(int2));
    int*   win_cursor = (int*)alloc((size_t)NWIN * WPAD * sizeof(int));
    uint2* pile     = (uint2*)alloc((size_t)NWIN * CAP * sizeof(uint2));                // 16.8 MB
    unsigned int* cv = (unsigned int*)alloc((size_t)NWIN * CAP * sizeof(unsigned int)); // 8.4 MB

    const int blk = 256;
    const int n4 = N_NODES * D_FEAT / 4;

    // ---- setup + CSR build; finesort (col-octant-grouped) fused with spmm pass 1 ----
    cursor_kernel<<<(NWIN + 255) / 256, 256, 0, stream>>>(win_cursor);
    bucket_kernel<<<EB_NB, EB_BS, 0, stream>>>(row, col, vals, win_cursor, pile, feat, feat16, n4);
    finesort_spmm1_kernel<<<NWIN, 1024, 0, stream>>>(pile, win_cursor, cv, row_rng, feat16, T1);

    // ---- remaining 3 bf16-state polynomial steps; h fused into the last ----
    const int sgrid = (N_NODES * 4 + blk - 1) / blk;
    spmm_kernel<<<sgrid, blk, 0, stream>>>(row_rng, cv, T1, T2, nullptr, nullptr, nullptr, theta, nullptr, 0);
    spmm_kernel<<<sgrid, blk, 0, stream>>>(row_rng, cv, T2, T3, nullptr, nullptr, nullptr, theta, nullptr, 0);
    spmm_kernel<<<sgrid, blk, 0, stream>>>(row_rng, cv, T3, nullptr, feat16, T1, T2, theta, h, 1);
}